// Round 1
// baseline (1599.587 us; speedup 1.0000x reference)
//
#include <hip/hip_runtime.h>
#include <cmath>

// ---------------- problem constants ----------------
// B=8, M=1024, D=768, N=32, P=32, K=8, H=2048
#define NB    8
#define MTOK  1024
#define BMT   8192      // B*M
#define DD    768
#define NEXP  32
#define PSLOT 32
#define NP    1024      // N*P
#define KTOP  8
#define HH    2048

// ---------------- K1: token L2 normalize ----------------
__global__ __launch_bounds__(256) void norm_x(const float* __restrict__ x, float* __restrict__ xn) {
    int tok = blockIdx.x;
    int t = threadIdx.x;
    const float* p = x + (long)tok * DD;
    float v0 = p[t], v1 = p[t + 256], v2 = p[t + 512];
    float ss = v0 * v0 + v1 * v1 + v2 * v2;
#pragma unroll
    for (int o = 32; o; o >>= 1) ss += __shfl_xor(ss, o);
    __shared__ float sred[4];
    if ((t & 63) == 0) sred[t >> 6] = ss;
    __syncthreads();
    ss = sred[0] + sred[1] + sred[2] + sred[3];
    float inv = 1.0f / fmaxf(sqrtf(ss), 1e-12f);
    float* q = xn + (long)tok * DD;
    q[t] = v0 * inv; q[t + 256] = v1 * inv; q[t + 512] = v2 * inv;
}

// ---------------- K2: phi normalize (over D) + scale ----------------
__global__ __launch_bounds__(256) void norm_phi(const float* __restrict__ phi, const float* __restrict__ scale,
                                                float* __restrict__ phin) {
    int np = blockIdx.x * 256 + threadIdx.x;   // 0..1023
    float ss = 0.f;
    for (int d = 0; d < DD; ++d) {
        float v = phi[(long)d * NP + np];
        ss += v * v;
    }
    float sc = scale[0] / fmaxf(sqrtf(ss), 1e-12f);
    for (int d = 0; d < DD; ++d)
        phin[(long)d * NP + np] = phi[(long)d * NP + np] * sc;
}

// ---------------- K3: per-cluster sums (deterministic partials) ----------------
// grid: (chunk=3, slice=16), block 256.  spart[slice][32][768], cntpart[slice][32]
__global__ __launch_bounds__(256) void cluster_sum(const float* __restrict__ xn, const int* __restrict__ ca,
                                                   float* __restrict__ spart, float* __restrict__ cntpart) {
    __shared__ float s[NEXP][256];
    __shared__ float cnt[NEXP];
    int chunk = blockIdx.x, slice = blockIdx.y, t = threadIdx.x;
#pragma unroll
    for (int n = 0; n < NEXP; ++n) s[n][t] = 0.f;
    if (t < NEXP) cnt[t] = 0.f;
    __syncthreads();
    int tok0 = slice * 512;
    for (int i = 0; i < 512; ++i) {
        int tok = tok0 + i;
        int a = ca[tok * KTOP];
        float v = xn[(long)tok * DD + chunk * 256 + t];
        s[a][t] += v;
        if (chunk == 0 && t == 0) cnt[a] += 1.f;
    }
    __syncthreads();
    for (int n = 0; n < NEXP; ++n)
        spart[(long)slice * (NEXP * DD) + n * DD + chunk * 256 + t] = s[n][t];
    if (chunk == 0 && t < NEXP) cntpart[slice * NEXP + t] = cnt[t];
}

// ---------------- K3b/K4b: reduce 16 partials (fixed order) ----------------
__global__ __launch_bounds__(256) void reduce_parts(const float* __restrict__ part, float* __restrict__ outv,
                                                    const float* __restrict__ cntpart, float* __restrict__ ccnt,
                                                    int doCnt) {
    int i = blockIdx.x * 256 + threadIdx.x;   // 0..24575
    float s = 0.f;
#pragma unroll
    for (int sl = 0; sl < 16; ++sl) s += part[(long)sl * (NEXP * DD) + i];
    outv[i] = s;
    if (doCnt && i < NEXP) {
        float c = 0.f;
#pragma unroll
        for (int sl = 0; sl < 16; ++sl) c += cntpart[sl * NEXP + i];
        ccnt[i] = c;
    }
}

// ---------------- K4: per-cluster MAD partials ----------------
__global__ __launch_bounds__(256) void cluster_mad(const float* __restrict__ xn, const int* __restrict__ ca,
                                                   const float* __restrict__ csum, const float* __restrict__ ccnt,
                                                   float* __restrict__ mpart) {
    __shared__ float md[NEXP][256];
    __shared__ float mean[NEXP][256];
    int chunk = blockIdx.x, slice = blockIdx.y, t = threadIdx.x;
#pragma unroll
    for (int n = 0; n < NEXP; ++n) {
        float c = ccnt[n];
        mean[n][t] = (c > 0.f) ? csum[n * DD + chunk * 256 + t] / c : 0.f;
        md[n][t] = 0.f;
    }
    __syncthreads();
    int tok0 = slice * 512;
    for (int i = 0; i < 512; ++i) {
        int tok = tok0 + i;
        int a = ca[tok * KTOP];
        float v = xn[(long)tok * DD + chunk * 256 + t];
        md[a][t] += fabsf(v - mean[a][t]);
    }
    __syncthreads();
    for (int n = 0; n < NEXP; ++n)
        mpart[(long)slice * (NEXP * DD) + n * DD + chunk * 256 + t] = md[n][t];
}

// ---------------- K5: W = normalize(clamp(1/(mad+0.35))) ----------------
__global__ __launch_bounds__(1024) void compute_W(const float* __restrict__ cmad, const float* __restrict__ ccnt,
                                                  float* __restrict__ W) {
    __shared__ float s[16];
    int t = threadIdx.x;
    auto block_sum = [&](float v) -> float {
#pragma unroll
        for (int o = 32; o; o >>= 1) v += __shfl_xor(v, o);
        if ((t & 63) == 0) s[t >> 6] = v;
        __syncthreads();
        float tot = 0.f;
#pragma unroll
        for (int i = 0; i < 16; ++i) tot += s[i];
        __syncthreads();
        return tot;
    };
    const int TOT = NEXP * DD;  // 24576
    float p = 0.f;
    for (int i = t; i < TOT; i += 1024) {
        int n = i / DD;
        float c = ccnt[n];
        float wm = (c > 0.f) ? cmad[i] / c : 0.f;
        p += 1.f / (wm + 0.35f);
    }
    float mean1 = block_sum(p) / (float)TOT;
    float clamp = 5.f * mean1;
    p = 0.f;
    for (int i = t; i < TOT; i += 1024) {
        int n = i / DD;
        float c = ccnt[n];
        float wm = (c > 0.f) ? cmad[i] / c : 0.f;
        p += fminf(1.f / (wm + 0.35f), clamp);
    }
    float mean2 = block_sum(p) / (float)TOT;
    float inv2 = 1.f / mean2;
    for (int i = t; i < TOT; i += 1024) {
        int n = i / DD;
        float c = ccnt[n];
        float wm = (c > 0.f) ? cmad[i] / c : 0.f;
        W[i] = fminf(1.f / (wm + 0.35f), clamp) * inv2;
    }
}

// ---------------- K6: xn *= W[assign] ----------------
__global__ __launch_bounds__(192) void apply_W(float* __restrict__ xn, const int* __restrict__ ca,
                                               const float* __restrict__ W) {
    int tok = blockIdx.x;
    int d4 = threadIdx.x * 4;
    int a = ca[tok * KTOP];
    float4 v = *reinterpret_cast<float4*>(xn + (long)tok * DD + d4);
    float4 w = *reinterpret_cast<const float4*>(W + a * DD + d4);
    v.x *= w.x; v.y *= w.y; v.z *= w.z; v.w *= w.w;
    *reinterpret_cast<float4*>(xn + (long)tok * DD + d4) = v;
}

// ---------------- generic f32 tiled GEMM 128x128, BK=16 ----------------
// TA: A stored [K x M] (transposed access). EMAP: expert row remap for A/C rows.
// SCALE: A scaled by exp(v - smax[m])*sinv[m] (m = GEMM M coordinate).
// EPI: 0 none, 1 +bias, 2 +bias then exact gelu.
template <bool TA, bool EMAP, bool SCALE, int EPI>
__global__ __launch_bounds__(256) void gemm_k(
    const float* __restrict__ A, const float* __restrict__ B, float* __restrict__ C,
    int M, int N, int K, int lda, int ldb, int ldc,
    long sA, long sB, long sC,
    const float* __restrict__ smax, const float* __restrict__ sinv, int sScale,
    const float* __restrict__ bias, int biasStride) {
    __shared__ float As[16][132];
    __shared__ float Bs[16][132];
    const int tid = threadIdx.x;
    const int z = blockIdx.z;
    const int m0 = blockIdx.y * 128;
    const int n0 = blockIdx.x * 128;
    const float* Bz = B + (long)z * sB;
    const int tx = tid & 15, ty = tid >> 4;

    float acc[8][8];
#pragma unroll
    for (int i = 0; i < 8; ++i)
#pragma unroll
        for (int j = 0; j < 8; ++j) acc[i][j] = 0.f;

    for (int k0 = 0; k0 < K; k0 += 16) {
        // ---- stage B tile [16][128]
#pragma unroll
        for (int i = 0; i < 2; ++i) {
            int lin = tid + i * 256;
            int kr = lin >> 5, n4 = (lin & 31) << 2;
            float4 v = *reinterpret_cast<const float4*>(Bz + (long)(k0 + kr) * ldb + (n0 + n4));
            *reinterpret_cast<float4*>(&Bs[kr][n4]) = v;
        }
        // ---- stage A tile into As[k][m]
        if constexpr (TA) {
#pragma unroll
            for (int i = 0; i < 2; ++i) {
                int lin = tid + i * 256;
                int kr = lin >> 5, m4 = (lin & 31) << 2;
                float4 v = *reinterpret_cast<const float4*>(A + (long)z * sA + (long)(k0 + kr) * lda + (m0 + m4));
                if constexpr (SCALE) {
                    float4 mx = *reinterpret_cast<const float4*>(smax + (long)z * sScale + m0 + m4);
                    float4 si = *reinterpret_cast<const float4*>(sinv + (long)z * sScale + m0 + m4);
                    v.x = __expf(v.x - mx.x) * si.x; v.y = __expf(v.y - mx.y) * si.y;
                    v.z = __expf(v.z - mx.z) * si.z; v.w = __expf(v.w - mx.w) * si.w;
                }
                *reinterpret_cast<float4*>(&As[kr][m4]) = v;
            }
        } else {
#pragma unroll
            for (int i = 0; i < 2; ++i) {
                int lin = tid + i * 256;
                int r = lin >> 2, k4 = (lin & 3) << 2;
                int rg = m0 + r;
                long roff;
                if constexpr (EMAP) roff = ((long)(rg >> 5) * NP + (long)z * PSLOT + (rg & 31)) * lda;
                else                roff = (long)z * sA + (long)rg * lda;
                float4 v = *reinterpret_cast<const float4*>(A + roff + k0 + k4);
                if constexpr (SCALE) {
                    float mx = smax[(long)z * sScale + rg], si = sinv[(long)z * sScale + rg];
                    v.x = __expf(v.x - mx) * si; v.y = __expf(v.y - mx) * si;
                    v.z = __expf(v.z - mx) * si; v.w = __expf(v.w - mx) * si;
                }
                As[k4 + 0][r] = v.x; As[k4 + 1][r] = v.y; As[k4 + 2][r] = v.z; As[k4 + 3][r] = v.w;
            }
        }
        __syncthreads();
#pragma unroll
        for (int kk = 0; kk < 16; ++kk) {
            float a[8], b[8];
            *reinterpret_cast<float4*>(&a[0]) = *reinterpret_cast<const float4*>(&As[kk][ty * 8]);
            *reinterpret_cast<float4*>(&a[4]) = *reinterpret_cast<const float4*>(&As[kk][ty * 8 + 4]);
            *reinterpret_cast<float4*>(&b[0]) = *reinterpret_cast<const float4*>(&Bs[kk][tx * 8]);
            *reinterpret_cast<float4*>(&b[4]) = *reinterpret_cast<const float4*>(&Bs[kk][tx * 8 + 4]);
#pragma unroll
            for (int i = 0; i < 8; ++i)
#pragma unroll
                for (int j = 0; j < 8; ++j) acc[i][j] = fmaf(a[i], b[j], acc[i][j]);
        }
        __syncthreads();
    }
    // ---- epilogue
#pragma unroll
    for (int i = 0; i < 8; ++i) {
        int rg = m0 + ty * 8 + i;
        long roff;
        if constexpr (EMAP) roff = ((long)(rg >> 5) * NP + (long)z * PSLOT + (rg & 31)) * ldc;
        else                roff = (long)z * sC + (long)rg * ldc;
        float vout[8];
#pragma unroll
        for (int j = 0; j < 8; ++j) {
            float v = acc[i][j];
            if constexpr (EPI >= 1) v += bias[(long)z * biasStride + (n0 + tx * 8 + j)];
            if constexpr (EPI == 2) v = 0.5f * v * (1.0f + erff(v * 0.70710678118654752f));
            vout[j] = v;
        }
        float* Cp = C + roff + n0 + tx * 8;
        *reinterpret_cast<float4*>(Cp)     = make_float4(vout[0], vout[1], vout[2], vout[3]);
        *reinterpret_cast<float4*>(Cp + 4) = make_float4(vout[4], vout[5], vout[6], vout[7]);
    }
}

// ---------------- K8: per-row top-8 + row softmax stats ----------------
__global__ __launch_bounds__(64) void row_topk(const float* __restrict__ logits,
                                               float* __restrict__ mix_out, float* __restrict__ clus_out,
                                               float* __restrict__ rowmax, float* __restrict__ rowsumInv) {
    int row = blockIdx.x;       // b*1024 + m
    int lane = threadIdx.x;
    const float* p = logits + (long)row * NP;
    float v[16];
#pragma unroll
    for (int i = 0; i < 16; ++i) v[i] = p[lane + i * 64];
    // row max
    float mx = v[0];
#pragma unroll
    for (int i = 1; i < 16; ++i) mx = fmaxf(mx, v[i]);
#pragma unroll
    for (int o = 32; o; o >>= 1) mx = fmaxf(mx, __shfl_xor(mx, o));
    // exp-sum
    float s = 0.f;
#pragma unroll
    for (int i = 0; i < 16; ++i) s += __expf(v[i] - mx);
#pragma unroll
    for (int o = 32; o; o >>= 1) s += __shfl_xor(s, o);
    if (lane == 0) { rowmax[row] = mx; rowsumInv[row] = 1.0f / s; }
    // iterative top-8 extraction (ties -> lowest index, matches lax.top_k)
#pragma unroll
    for (int k = 0; k < KTOP; ++k) {
        float bv = -INFINITY; int bi = 1 << 30;
#pragma unroll
        for (int i = 0; i < 16; ++i) {
            if (v[i] > bv) { bv = v[i]; bi = lane + i * 64; }   // ascending idx: > keeps lowest
        }
#pragma unroll
        for (int o = 32; o; o >>= 1) {
            float ov = __shfl_xor(bv, o); int oi = __shfl_xor(bi, o);
            if (ov > bv || (ov == bv && oi < bi)) { bv = ov; bi = oi; }
        }
        int owner = bi & 63, slot = bi >> 6;
        if (lane == owner) {
#pragma unroll
            for (int i = 0; i < 16; ++i) if (slot == i) v[i] = -INFINITY;
        }
        if (lane == k) {
            mix_out[(long)row * KTOP + k] = bv;
            clus_out[(long)row * KTOP + k] = (float)(bi >> 5);   // slot // P
        }
    }
}

// ---------------- K9: column softmax stats (over tokens m), partial ----------------
// grid: (npc=4, ms=8, b=8), block 256
__global__ __launch_bounds__(256) void col_stats_part(const float* __restrict__ logits,
                                                      float* __restrict__ pmax, float* __restrict__ psum) {
    int b = blockIdx.z, ms = blockIdx.y, npc = blockIdx.x;
    int np = npc * 256 + threadIdx.x;
    const float* p = logits + ((long)b * MTOK + ms * 128) * NP + np;
    float mx = -INFINITY, s = 0.f;
    for (int m = 0; m < 128; ++m) {
        float v = p[(long)m * NP];
        float nm = fmaxf(mx, v);
        s = s * __expf(mx - nm) + __expf(v - nm);
        mx = nm;
    }
    long o = ((long)b * 8 + ms) * NP + np;
    pmax[o] = mx; psum[o] = s;
}

__global__ __launch_bounds__(256) void col_stats_merge(const float* __restrict__ pmax, const float* __restrict__ psum,
                                                       float* __restrict__ cmax, float* __restrict__ csumInv) {
    int b = blockIdx.y;
    int np = blockIdx.x * 256 + threadIdx.x;
    float mx = -INFINITY;
#pragma unroll
    for (int ms = 0; ms < 8; ++ms) mx = fmaxf(mx, pmax[((long)b * 8 + ms) * NP + np]);
    float s = 0.f;
#pragma unroll
    for (int ms = 0; ms < 8; ++ms) {
        long o = ((long)b * 8 + ms) * NP + np;
        s += psum[o] * __expf(pmax[o] - mx);
    }
    cmax[(long)b * NP + np] = mx;
    csumInv[(long)b * NP + np] = 1.0f / s;
}

// ---------------- launch ----------------
extern "C" void kernel_launch(void* const* d_in, const int* in_sizes, int n_in,
                              void* d_out, int out_size, void* d_ws, size_t ws_size,
                              hipStream_t stream) {
    const float* x    = (const float*)d_in[0];
    const int*   ca   = (const int*)d_in[1];
    const float* phi  = (const float*)d_in[2];
    const float* scale= (const float*)d_in[3];
    const float* w1   = (const float*)d_in[4];
    const float* b1   = (const float*)d_in[5];
    const float* w2   = (const float*)d_in[6];
    const float* b2   = (const float*)d_in[7];
    float* out = (float*)d_out;
    float* ws  = (float*)d_ws;

    float* xn        = ws;                   // 6291456
    float* phin      = xn + 6291456;         // 786432
    float* logits    = phin + 786432;        // 8388608
    float* xs        = logits + 8388608;     // 6291456
    float* h         = xs + 6291456;         // 16777216
    float* rowmax    = h + 16777216;         // 8192
    float* rowsumInv = rowmax + 8192;        // 8192
    float* colmax    = rowsumInv + 8192;     // 8192
    float* colsumInv = colmax + 8192;        // 8192
    float* pmax      = colsumInv + 8192;     // 65536
    float* psum      = pmax + 65536;         // 65536
    float* csum      = psum + 65536;         // 24576
    float* cmad      = csum + 24576;         // 24576
    float* Wbuf      = cmad + 24576;         // 24576
    float* ccnt      = Wbuf + 24576;         // 64
    float* spart     = ccnt + 64;            // 393216
    float* mpart     = spart + 393216;       // 393216
    float* cntpart   = mpart + 393216;       // 512
    float* ys        = xn;                   // alias: xn dead after xs GEMM

    float* out_y    = out;                         // 6291456
    float* out_mix  = out + 6291456;               // 65536
    float* out_clus = out + 6291456 + 65536;       // 65536

    norm_x<<<BMT, 256, 0, stream>>>(x, xn);
    norm_phi<<<4, 256, 0, stream>>>(phi, scale, phin);

    cluster_sum<<<dim3(3, 16), 256, 0, stream>>>(xn, ca, spart, cntpart);
    reduce_parts<<<96, 256, 0, stream>>>(spart, csum, cntpart, ccnt, 1);
    cluster_mad<<<dim3(3, 16), 256, 0, stream>>>(xn, ca, csum, ccnt, mpart);
    reduce_parts<<<96, 256, 0, stream>>>(mpart, cmad, nullptr, nullptr, 0);
    compute_W<<<1, 1024, 0, stream>>>(cmad, ccnt, Wbuf);
    apply_W<<<BMT, 192, 0, stream>>>(xn, ca, Wbuf);

    // logits = xn_w [8192x768] . phin [768x1024]
    gemm_k<false, false, false, 0><<<dim3(8, 64, 1), 256, 0, stream>>>(
        xn, phin, logits, BMT, NP, DD, DD, NP, NP, 0, 0, 0, nullptr, nullptr, 0, nullptr, 0);

    row_topk<<<BMT, 64, 0, stream>>>(logits, out_mix, out_clus, rowmax, rowsumInv);
    col_stats_part<<<dim3(4, 8, NB), 256, 0, stream>>>(logits, pmax, psum);
    col_stats_merge<<<dim3(4, NB), 256, 0, stream>>>(pmax, psum, colmax, colsumInv);

    // xs[b] = disp^T [1024np x 1024m] . xn[b] [1024m x 768]   (disp from logits on the fly)
    gemm_k<true, false, true, 0><<<dim3(6, 8, NB), 256, 0, stream>>>(
        logits, xn, xs, NP, DD, MTOK, NP, DD, DD,
        (long)MTOK * NP, (long)MTOK * DD, (long)NP * DD, colmax, colsumInv, NP, nullptr, 0);

    // h[n] = gelu( xs_rows(n) [256x768] . w1[n] [768x2048] + b1[n] )
    gemm_k<false, true, false, 2><<<dim3(16, 2, NEXP), 256, 0, stream>>>(
        xs, w1, h, 256, HH, DD, DD, HH, HH,
        0, (long)DD * HH, 0, nullptr, nullptr, 0, b1, HH);

    // ys[n] = h_rows(n) [256x2048] . w2[n] [2048x768] + b2[n]
    gemm_k<false, true, false, 1><<<dim3(6, 2, NEXP), 256, 0, stream>>>(
        h, w2, ys, 256, DD, HH, HH, DD, DD,
        0, (long)HH * DD, 0, nullptr, nullptr, 0, b2, DD);

    // y[b] = comb [1024m x 1024np] . ys[b] [1024np x 768]   (comb from logits on the fly)
    gemm_k<false, false, true, 0><<<dim3(6, 8, NB), 256, 0, stream>>>(
        logits, ys, out_y, MTOK, DD, NP, NP, DD, DD,
        (long)MTOK * NP, (long)NP * DD, (long)MTOK * DD, rowmax, rowsumInv, NP, nullptr, 0);
}

// Round 2
// 1002.231 us; speedup vs baseline: 1.5960x; 1.5960x over previous
//
#include <hip/hip_runtime.h>
#include <cmath>

// ---------------- problem constants ----------------
// B=8, M=1024, D=768, N=32, P=32, K=8, H=2048
#define NB    8
#define MTOK  1024
#define BMT   8192      // B*M
#define DD    768
#define NEXP  32
#define PSLOT 32
#define NP    1024      // N*P
#define KTOP  8
#define HH    2048

typedef unsigned short ushort;
typedef __attribute__((ext_vector_type(8))) short short8v;   // 8 bf16 = 4 VGPR
typedef __attribute__((ext_vector_type(4))) short short4v;   // 8 bytes
typedef __attribute__((ext_vector_type(4))) float f32x4;

// f32 -> bf16 round-to-nearest-even
__device__ __forceinline__ ushort bf16_rne(float x) {
    unsigned u = __float_as_uint(x);
    unsigned r = (u + 0x7FFFu + ((u >> 16) & 1u)) >> 16;
    return (ushort)r;
}
__device__ __forceinline__ float bf16_to_f(ushort h) {
    return __uint_as_float(((unsigned)h) << 16);
}
__device__ __forceinline__ void split2(float x, ushort& hi, ushort& lo) {
    hi = bf16_rne(x);
    lo = bf16_rne(x - bf16_to_f(hi));
}

// ---------------- K1: token L2 normalize ----------------
__global__ __launch_bounds__(256) void norm_x(const float* __restrict__ x, float* __restrict__ xn) {
    int tok = blockIdx.x;
    int t = threadIdx.x;
    const float* p = x + (long)tok * DD;
    float v0 = p[t], v1 = p[t + 256], v2 = p[t + 512];
    float ss = v0 * v0 + v1 * v1 + v2 * v2;
#pragma unroll
    for (int o = 32; o; o >>= 1) ss += __shfl_xor(ss, o);
    __shared__ float sred[4];
    if ((t & 63) == 0) sred[t >> 6] = ss;
    __syncthreads();
    ss = sred[0] + sred[1] + sred[2] + sred[3];
    float inv = 1.0f / fmaxf(sqrtf(ss), 1e-12f);
    float* q = xn + (long)tok * DD;
    q[t] = v0 * inv; q[t + 256] = v1 * inv; q[t + 512] = v2 * inv;
}

// ---------------- K2: phi normalize (over D) + scale ----------------
__global__ __launch_bounds__(256) void norm_phi(const float* __restrict__ phi, const float* __restrict__ scale,
                                                float* __restrict__ phin) {
    int np = blockIdx.x * 256 + threadIdx.x;   // 0..1023
    float ss = 0.f;
    for (int d = 0; d < DD; ++d) {
        float v = phi[(long)d * NP + np];
        ss += v * v;
    }
    float sc = scale[0] / fmaxf(sqrtf(ss), 1e-12f);
    for (int d = 0; d < DD; ++d)
        phin[(long)d * NP + np] = phi[(long)d * NP + np] * sc;
}

// ---------------- K3: per-cluster sums (deterministic partials) ----------------
__global__ __launch_bounds__(256) void cluster_sum(const float* __restrict__ xn, const int* __restrict__ ca,
                                                   float* __restrict__ spart, float* __restrict__ cntpart) {
    __shared__ float s[NEXP][256];
    __shared__ float cnt[NEXP];
    int chunk = blockIdx.x, slice = blockIdx.y, t = threadIdx.x;
#pragma unroll
    for (int n = 0; n < NEXP; ++n) s[n][t] = 0.f;
    if (t < NEXP) cnt[t] = 0.f;
    __syncthreads();
    int tok0 = slice * 512;
    for (int i = 0; i < 512; ++i) {
        int tok = tok0 + i;
        int a = ca[tok * KTOP];
        float v = xn[(long)tok * DD + chunk * 256 + t];
        s[a][t] += v;
        if (chunk == 0 && t == 0) cnt[a] += 1.f;
    }
    __syncthreads();
    for (int n = 0; n < NEXP; ++n)
        spart[(long)slice * (NEXP * DD) + n * DD + chunk * 256 + t] = s[n][t];
    if (chunk == 0 && t < NEXP) cntpart[slice * NEXP + t] = cnt[t];
}

__global__ __launch_bounds__(256) void reduce_parts(const float* __restrict__ part, float* __restrict__ outv,
                                                    const float* __restrict__ cntpart, float* __restrict__ ccnt,
                                                    int doCnt) {
    int i = blockIdx.x * 256 + threadIdx.x;   // 0..24575
    float s = 0.f;
#pragma unroll
    for (int sl = 0; sl < 16; ++sl) s += part[(long)sl * (NEXP * DD) + i];
    outv[i] = s;
    if (doCnt && i < NEXP) {
        float c = 0.f;
#pragma unroll
        for (int sl = 0; sl < 16; ++sl) c += cntpart[sl * NEXP + i];
        ccnt[i] = c;
    }
}

// ---------------- K4: per-cluster MAD partials ----------------
__global__ __launch_bounds__(256) void cluster_mad(const float* __restrict__ xn, const int* __restrict__ ca,
                                                   const float* __restrict__ csum, const float* __restrict__ ccnt,
                                                   float* __restrict__ mpart) {
    __shared__ float md[NEXP][256];
    __shared__ float mean[NEXP][256];
    int chunk = blockIdx.x, slice = blockIdx.y, t = threadIdx.x;
#pragma unroll
    for (int n = 0; n < NEXP; ++n) {
        float c = ccnt[n];
        mean[n][t] = (c > 0.f) ? csum[n * DD + chunk * 256 + t] / c : 0.f;
        md[n][t] = 0.f;
    }
    __syncthreads();
    int tok0 = slice * 512;
    for (int i = 0; i < 512; ++i) {
        int tok = tok0 + i;
        int a = ca[tok * KTOP];
        float v = xn[(long)tok * DD + chunk * 256 + t];
        md[a][t] += fabsf(v - mean[a][t]);
    }
    __syncthreads();
    for (int n = 0; n < NEXP; ++n)
        mpart[(long)slice * (NEXP * DD) + n * DD + chunk * 256 + t] = md[n][t];
}

// ---------------- K5: W = normalize(clamp(1/(mad+0.35))) ----------------
__global__ __launch_bounds__(1024) void compute_W(const float* __restrict__ cmad, const float* __restrict__ ccnt,
                                                  float* __restrict__ W) {
    __shared__ float s[16];
    int t = threadIdx.x;
    auto block_sum = [&](float v) -> float {
#pragma unroll
        for (int o = 32; o; o >>= 1) v += __shfl_xor(v, o);
        if ((t & 63) == 0) s[t >> 6] = v;
        __syncthreads();
        float tot = 0.f;
#pragma unroll
        for (int i = 0; i < 16; ++i) tot += s[i];
        __syncthreads();
        return tot;
    };
    const int TOT = NEXP * DD;  // 24576
    float p = 0.f;
    for (int i = t; i < TOT; i += 1024) {
        int n = i / DD;
        float c = ccnt[n];
        float wm = (c > 0.f) ? cmad[i] / c : 0.f;
        p += 1.f / (wm + 0.35f);
    }
    float mean1 = block_sum(p) / (float)TOT;
    float clamp = 5.f * mean1;
    p = 0.f;
    for (int i = t; i < TOT; i += 1024) {
        int n = i / DD;
        float c = ccnt[n];
        float wm = (c > 0.f) ? cmad[i] / c : 0.f;
        p += fminf(1.f / (wm + 0.35f), clamp);
    }
    float mean2 = block_sum(p) / (float)TOT;
    float inv2 = 1.f / mean2;
    for (int i = t; i < TOT; i += 1024) {
        int n = i / DD;
        float c = ccnt[n];
        float wm = (c > 0.f) ? cmad[i] / c : 0.f;
        W[i] = fminf(1.f / (wm + 0.35f), clamp) * inv2;
    }
}

// ---------------- K6: xn *= W[assign] ----------------
__global__ __launch_bounds__(192) void apply_W(float* __restrict__ xn, const int* __restrict__ ca,
                                               const float* __restrict__ W) {
    int tok = blockIdx.x;
    int d4 = threadIdx.x * 4;
    int a = ca[tok * KTOP];
    float4 v = *reinterpret_cast<float4*>(xn + (long)tok * DD + d4);
    float4 w = *reinterpret_cast<const float4*>(W + a * DD + d4);
    v.x *= w.x; v.y *= w.y; v.z *= w.z; v.w *= w.w;
    *reinterpret_cast<float4*>(xn + (long)tok * DD + d4) = v;
}

// ---------------- f32 tiled GEMM (logits only) ----------------
__global__ __launch_bounds__(256) void gemm_f32(
    const float* __restrict__ A, const float* __restrict__ B, float* __restrict__ C,
    int M, int N, int K, int lda, int ldb, int ldc) {
    __shared__ float As[16][132];
    __shared__ float Bs[16][132];
    const int tid = threadIdx.x;
    const int m0 = blockIdx.y * 128;
    const int n0 = blockIdx.x * 128;
    const int tx = tid & 15, ty = tid >> 4;

    float acc[8][8];
#pragma unroll
    for (int i = 0; i < 8; ++i)
#pragma unroll
        for (int j = 0; j < 8; ++j) acc[i][j] = 0.f;

    for (int k0 = 0; k0 < K; k0 += 16) {
#pragma unroll
        for (int i = 0; i < 2; ++i) {
            int lin = tid + i * 256;
            int kr = lin >> 5, n4 = (lin & 31) << 2;
            float4 v = *reinterpret_cast<const float4*>(B + (long)(k0 + kr) * ldb + (n0 + n4));
            *reinterpret_cast<float4*>(&Bs[kr][n4]) = v;
        }
#pragma unroll
        for (int i = 0; i < 2; ++i) {
            int lin = tid + i * 256;
            int r = lin >> 2, k4 = (lin & 3) << 2;
            float4 v = *reinterpret_cast<const float4*>(A + (long)(m0 + r) * lda + k0 + k4);
            As[k4 + 0][r] = v.x; As[k4 + 1][r] = v.y; As[k4 + 2][r] = v.z; As[k4 + 3][r] = v.w;
        }
        __syncthreads();
#pragma unroll
        for (int kk = 0; kk < 16; ++kk) {
            float a[8], b[8];
            *reinterpret_cast<float4*>(&a[0]) = *reinterpret_cast<const float4*>(&As[kk][ty * 8]);
            *reinterpret_cast<float4*>(&a[4]) = *reinterpret_cast<const float4*>(&As[kk][ty * 8 + 4]);
            *reinterpret_cast<float4*>(&b[0]) = *reinterpret_cast<const float4*>(&Bs[kk][tx * 8]);
            *reinterpret_cast<float4*>(&b[4]) = *reinterpret_cast<const float4*>(&Bs[kk][tx * 8 + 4]);
#pragma unroll
            for (int i = 0; i < 8; ++i)
#pragma unroll
                for (int j = 0; j < 8; ++j) acc[i][j] = fmaf(a[i], b[j], acc[i][j]);
        }
        __syncthreads();
    }
#pragma unroll
    for (int i = 0; i < 8; ++i) {
        float* Cp = C + (long)(m0 + ty * 8 + i) * ldc + n0 + tx * 8;
        *reinterpret_cast<float4*>(Cp)     = make_float4(acc[i][0], acc[i][1], acc[i][2], acc[i][3]);
        *reinterpret_cast<float4*>(Cp + 4) = make_float4(acc[i][4], acc[i][5], acc[i][6], acc[i][7]);
    }
}

// ---------------- MFMA split-bf16 GEMM 128x128, BK=32 ----------------
// AMODE 0: A from pre-split bf16 (Ahi/Alo), rows via expert remap (EMAP).
// AMODE 1: A from f32, k-contiguous rows, per-row softmax scale exp(v-smax)*sinv.
// AMODE 2: A from f32 transposed (element (r,k) at Af32[k*lda+r]), per-row scale.
// EPI: 0 none, 1 +bias, 2 +bias+gelu.  WSPLIT: C -> (Chi,Clo) bf16 pair, else f32.
// CEMAP: expert remap on C rows.
template <int AMODE, int EPI, bool WSPLIT, bool CEMAP>
__global__ __launch_bounds__(256) void gemm_mfma(
    const ushort* __restrict__ Ahi, const ushort* __restrict__ Alo,
    const float* __restrict__ Af32,
    const float* __restrict__ B,
    float* __restrict__ Cf, ushort* __restrict__ Chi, ushort* __restrict__ Clo,
    int M, int N, int K, int lda, int ldb, int ldc,
    long sA, long sB, long sC,
    const float* __restrict__ smax, const float* __restrict__ sinv, int sScale,
    const float* __restrict__ bias, int biasStride) {
    // LDS: [row][40] bf16, padded 40 shorts (80B) -> b128 frag reads 2-way banked (free)
    __shared__ ushort Ah[128 * 40];
    __shared__ ushort Al[128 * 40];
    __shared__ ushort Bh[128 * 40];
    __shared__ ushort Bl[128 * 40];

    const int tid = threadIdx.x;
    const int z = blockIdx.z;
    const int m0 = blockIdx.y * 128;
    const int n0 = blockIdx.x * 128;
    const int lane = tid & 63, w = tid >> 6;
    const int wr = w >> 1, wc = w & 1;            // wave tile (64x64)
    const int lr = lane & 15, kh = lane >> 4;

    f32x4 acc[4][4];
#pragma unroll
    for (int i = 0; i < 4; ++i)
#pragma unroll
        for (int j = 0; j < 4; ++j) acc[i][j] = (f32x4)(0.f);

    const long zs = (long)z * sScale;

    for (int kk0 = 0; kk0 < K; kk0 += 32) {
        // ---------- stage A ----------
        if constexpr (AMODE == 0) {
#pragma unroll
            for (int i = 0; i < 2; ++i) {
                int g = tid + i * 256;            // 0..511
                int r = g >> 2, kg = g & 3;
                int rg = m0 + r;
                long roff = ((long)(rg >> 5) * NP + (long)z * PSLOT + (rg & 31)) * lda;
                long o = roff + kk0 + kg * 8;
                *reinterpret_cast<short8v*>(&Ah[r * 40 + kg * 8]) =
                    *reinterpret_cast<const short8v*>(Ahi + o);
                *reinterpret_cast<short8v*>(&Al[r * 40 + kg * 8]) =
                    *reinterpret_cast<const short8v*>(Alo + o);
            }
        } else if constexpr (AMODE == 1) {
#pragma unroll
            for (int i = 0; i < 4; ++i) {
                int g = tid + i * 256;            // 0..1023
                int r = g >> 3, kq = g & 7;
                int rg = m0 + r;
                float4 v = *reinterpret_cast<const float4*>(Af32 + (long)z * sA + (long)rg * lda + kk0 + kq * 4);
                float mx = smax[zs + rg], si = sinv[zs + rg];
                float f[4] = {__expf(v.x - mx) * si, __expf(v.y - mx) * si,
                              __expf(v.z - mx) * si, __expf(v.w - mx) * si};
                ushort h[4], l[4];
#pragma unroll
                for (int e = 0; e < 4; ++e) split2(f[e], h[e], l[e]);
                *reinterpret_cast<short4v*>(&Ah[r * 40 + kq * 4]) = short4v{(short)h[0], (short)h[1], (short)h[2], (short)h[3]};
                *reinterpret_cast<short4v*>(&Al[r * 40 + kq * 4]) = short4v{(short)l[0], (short)l[1], (short)l[2], (short)l[3]};
            }
        } else {  // AMODE 2: transposed 4x4 micro-transpose
            int r0 = (tid & 31) * 4;              // GEMM rows (contiguous in global)
            int kq = tid >> 5;                    // 0..7 -> k quad
            float vals[4][4];                     // [dk][dr]
#pragma unroll
            for (int dk = 0; dk < 4; ++dk) {
                float4 v = *reinterpret_cast<const float4*>(
                    Af32 + (long)z * sA + (long)(kk0 + kq * 4 + dk) * lda + m0 + r0);
                vals[dk][0] = v.x; vals[dk][1] = v.y; vals[dk][2] = v.z; vals[dk][3] = v.w;
            }
            float4 mx4 = *reinterpret_cast<const float4*>(smax + zs + m0 + r0);
            float4 si4 = *reinterpret_cast<const float4*>(sinv + zs + m0 + r0);
            float mxa[4] = {mx4.x, mx4.y, mx4.z, mx4.w};
            float sia[4] = {si4.x, si4.y, si4.z, si4.w};
            ushort h[4][4], l[4][4];
#pragma unroll
            for (int dk = 0; dk < 4; ++dk)
#pragma unroll
                for (int dr = 0; dr < 4; ++dr) {
                    float f = __expf(vals[dk][dr] - mxa[dr]) * sia[dr];
                    split2(f, h[dk][dr], l[dk][dr]);
                }
#pragma unroll
            for (int dr = 0; dr < 4; ++dr) {
                *reinterpret_cast<short4v*>(&Ah[(r0 + dr) * 40 + kq * 4]) =
                    short4v{(short)h[0][dr], (short)h[1][dr], (short)h[2][dr], (short)h[3][dr]};
                *reinterpret_cast<short4v*>(&Al[(r0 + dr) * 40 + kq * 4]) =
                    short4v{(short)l[0][dr], (short)l[1][dr], (short)l[2][dr], (short)l[3][dr]};
            }
        }
        // ---------- stage B (f32 [k][n] -> LDS [n][k], 4x4 micro-transpose) ----------
        {
            int n0q = (tid & 31) * 4;
            int kq = tid >> 5;
            float vals[4][4];                     // [dk][dn]
#pragma unroll
            for (int dk = 0; dk < 4; ++dk) {
                float4 v = *reinterpret_cast<const float4*>(
                    B + (long)z * sB + (long)(kk0 + kq * 4 + dk) * ldb + n0 + n0q);
                vals[dk][0] = v.x; vals[dk][1] = v.y; vals[dk][2] = v.z; vals[dk][3] = v.w;
            }
            ushort h[4][4], l[4][4];
#pragma unroll
            for (int dk = 0; dk < 4; ++dk)
#pragma unroll
                for (int dn = 0; dn < 4; ++dn) split2(vals[dk][dn], h[dk][dn], l[dk][dn]);
#pragma unroll
            for (int dn = 0; dn < 4; ++dn) {
                *reinterpret_cast<short4v*>(&Bh[(n0q + dn) * 40 + kq * 4]) =
                    short4v{(short)h[0][dn], (short)h[1][dn], (short)h[2][dn], (short)h[3][dn]};
                *reinterpret_cast<short4v*>(&Bl[(n0q + dn) * 40 + kq * 4]) =
                    short4v{(short)l[0][dn], (short)l[1][dn], (short)l[2][dn], (short)l[3][dn]};
            }
        }
        __syncthreads();
        // ---------- fragments + MFMA ----------
        short8v a_h[4], a_l[4], b_h[4], b_l[4];
#pragma unroll
        for (int mi = 0; mi < 4; ++mi) {
            int row = wr * 64 + mi * 16 + lr;
            a_h[mi] = *reinterpret_cast<const short8v*>(&Ah[row * 40 + kh * 8]);
            a_l[mi] = *reinterpret_cast<const short8v*>(&Al[row * 40 + kh * 8]);
        }
#pragma unroll
        for (int nj = 0; nj < 4; ++nj) {
            int row = wc * 64 + nj * 16 + lr;
            b_h[nj] = *reinterpret_cast<const short8v*>(&Bh[row * 40 + kh * 8]);
            b_l[nj] = *reinterpret_cast<const short8v*>(&Bl[row * 40 + kh * 8]);
        }
#pragma unroll
        for (int mi = 0; mi < 4; ++mi)
#pragma unroll
            for (int nj = 0; nj < 4; ++nj) {
                acc[mi][nj] = __builtin_amdgcn_mfma_f32_16x16x32_bf16(a_h[mi], b_h[nj], acc[mi][nj], 0, 0, 0);
                acc[mi][nj] = __builtin_amdgcn_mfma_f32_16x16x32_bf16(a_h[mi], b_l[nj], acc[mi][nj], 0, 0, 0);
                acc[mi][nj] = __builtin_amdgcn_mfma_f32_16x16x32_bf16(a_l[mi], b_h[nj], acc[mi][nj], 0, 0, 0);
            }
        __syncthreads();
    }
    // ---------- epilogue ----------
#pragma unroll
    for (int mi = 0; mi < 4; ++mi)
#pragma unroll
        for (int j = 0; j < 4; ++j) {
            int rg = m0 + wr * 64 + mi * 16 + kh * 4 + j;
            long roff;
            if constexpr (CEMAP) roff = ((long)(rg >> 5) * NP + (long)z * PSLOT + (rg & 31)) * ldc;
            else                 roff = (long)z * sC + (long)rg * ldc;
#pragma unroll
            for (int nj = 0; nj < 4; ++nj) {
                int col = n0 + wc * 64 + nj * 16 + lr;
                float v = acc[mi][nj][j];
                if constexpr (EPI >= 1) v += bias[(long)z * biasStride + col];
                if constexpr (EPI == 2) v = 0.5f * v * (1.0f + erff(v * 0.70710678118654752f));
                if constexpr (WSPLIT) {
                    ushort h, l; split2(v, h, l);
                    Chi[roff + col] = h; Clo[roff + col] = l;
                } else {
                    Cf[roff + col] = v;
                }
            }
        }
}

// ---------------- K8: per-row top-8 + row softmax stats ----------------
__global__ __launch_bounds__(64) void row_topk(const float* __restrict__ logits,
                                               float* __restrict__ mix_out, float* __restrict__ clus_out,
                                               float* __restrict__ rowmax, float* __restrict__ rowsumInv) {
    int row = blockIdx.x;
    int lane = threadIdx.x;
    const float* p = logits + (long)row * NP;
    float v[16];
#pragma unroll
    for (int i = 0; i < 16; ++i) v[i] = p[lane + i * 64];
    float mx = v[0];
#pragma unroll
    for (int i = 1; i < 16; ++i) mx = fmaxf(mx, v[i]);
#pragma unroll
    for (int o = 32; o; o >>= 1) mx = fmaxf(mx, __shfl_xor(mx, o));
    float s = 0.f;
#pragma unroll
    for (int i = 0; i < 16; ++i) s += __expf(v[i] - mx);
#pragma unroll
    for (int o = 32; o; o >>= 1) s += __shfl_xor(s, o);
    if (lane == 0) { rowmax[row] = mx; rowsumInv[row] = 1.0f / s; }
#pragma unroll
    for (int k = 0; k < KTOP; ++k) {
        float bv = -INFINITY; int bi = 1 << 30;
#pragma unroll
        for (int i = 0; i < 16; ++i) {
            if (v[i] > bv) { bv = v[i]; bi = lane + i * 64; }
        }
#pragma unroll
        for (int o = 32; o; o >>= 1) {
            float ov = __shfl_xor(bv, o); int oi = __shfl_xor(bi, o);
            if (ov > bv || (ov == bv && oi < bi)) { bv = ov; bi = oi; }
        }
        int owner = bi & 63, slot = bi >> 6;
        if (lane == owner) {
#pragma unroll
            for (int i = 0; i < 16; ++i) if (slot == i) v[i] = -INFINITY;
        }
        if (lane == k) {
            mix_out[(long)row * KTOP + k] = bv;
            clus_out[(long)row * KTOP + k] = (float)(bi >> 5);
        }
    }
}

// ---------------- K9: column softmax stats ----------------
__global__ __launch_bounds__(256) void col_stats_part(const float* __restrict__ logits,
                                                      float* __restrict__ pmax, float* __restrict__ psum) {
    int b = blockIdx.z, ms = blockIdx.y, npc = blockIdx.x;
    int np = npc * 256 + threadIdx.x;
    const float* p = logits + ((long)b * MTOK + ms * 128) * NP + np;
    float mx = -INFINITY, s = 0.f;
    for (int m = 0; m < 128; ++m) {
        float v = p[(long)m * NP];
        float nm = fmaxf(mx, v);
        s = s * __expf(mx - nm) + __expf(v - nm);
        mx = nm;
    }
    long o = ((long)b * 8 + ms) * NP + np;
    pmax[o] = mx; psum[o] = s;
}

__global__ __launch_bounds__(256) void col_stats_merge(const float* __restrict__ pmax, const float* __restrict__ psum,
                                                       float* __restrict__ cmax, float* __restrict__ csumInv) {
    int b = blockIdx.y;
    int np = blockIdx.x * 256 + threadIdx.x;
    float mx = -INFINITY;
#pragma unroll
    for (int ms = 0; ms < 8; ++ms) mx = fmaxf(mx, pmax[((long)b * 8 + ms) * NP + np]);
    float s = 0.f;
#pragma unroll
    for (int ms = 0; ms < 8; ++ms) {
        long o = ((long)b * 8 + ms) * NP + np;
        s += psum[o] * __expf(pmax[o] - mx);
    }
    cmax[(long)b * NP + np] = mx;
    csumInv[(long)b * NP + np] = 1.0f / s;
}

// ---------------- launch ----------------
extern "C" void kernel_launch(void* const* d_in, const int* in_sizes, int n_in,
                              void* d_out, int out_size, void* d_ws, size_t ws_size,
                              hipStream_t stream) {
    const float* x    = (const float*)d_in[0];
    const int*   ca   = (const int*)d_in[1];
    const float* phi  = (const float*)d_in[2];
    const float* scale= (const float*)d_in[3];
    const float* w1   = (const float*)d_in[4];
    const float* b1   = (const float*)d_in[5];
    const float* w2   = (const float*)d_in[6];
    const float* b2   = (const float*)d_in[7];
    float* out = (float*)d_out;
    float* ws  = (float*)d_ws;

    float* xn        = ws;                    // 6291456 f32
    float* phin      = xn + 6291456;          // 786432
    float* logits    = phin + 786432;         // 8388608
    ushort* xs_hi    = (ushort*)(logits + 8388608);   // 6291456 shorts (3145728 f32)
    ushort* xs_lo    = xs_hi + 6291456;               // 6291456 shorts
    ushort* h_hi     = (ushort*)((float*)xs_hi + 6291456);  // 16777216 shorts
    ushort* h_lo     = h_hi + 16777216;
    float* after_h   = (float*)xs_hi + 6291456 + 16777216;  // f32 cursor after splits
    float* rowmax    = after_h;               // 8192
    float* rowsumInv = rowmax + 8192;
    float* colmax    = rowsumInv + 8192;
    float* colsumInv = colmax + 8192;
    float* pmax      = colsumInv + 8192;      // 65536
    float* psum      = pmax + 65536;          // 65536
    float* csum      = psum + 65536;          // 24576
    float* cmad      = csum + 24576;          // 24576
    float* Wbuf      = cmad + 24576;          // 24576
    float* ccnt      = Wbuf + 24576;          // 64
    float* spart     = ccnt + 64;             // 393216
    float* mpart     = spart + 393216;        // 393216
    float* cntpart   = mpart + 393216;        // 512
    float* ys        = xn;                    // alias: xn dead after xs GEMM

    float* out_y    = out;
    float* out_mix  = out + 6291456;
    float* out_clus = out + 6291456 + 65536;

    norm_x<<<BMT, 256, 0, stream>>>(x, xn);
    norm_phi<<<4, 256, 0, stream>>>(phi, scale, phin);

    cluster_sum<<<dim3(3, 16), 256, 0, stream>>>(xn, ca, spart, cntpart);
    reduce_parts<<<96, 256, 0, stream>>>(spart, csum, cntpart, ccnt, 1);
    cluster_mad<<<dim3(3, 16), 256, 0, stream>>>(xn, ca, csum, ccnt, mpart);
    reduce_parts<<<96, 256, 0, stream>>>(mpart, cmad, nullptr, nullptr, 0);
    compute_W<<<1, 1024, 0, stream>>>(cmad, ccnt, Wbuf);
    apply_W<<<BMT, 192, 0, stream>>>(xn, ca, Wbuf);

    // logits = xn_w [8192x768] . phin [768x1024]  (f32 vector GEMM: top-k exactness)
    gemm_f32<<<dim3(8, 64, 1), 256, 0, stream>>>(
        xn, phin, logits, BMT, NP, DD, DD, NP, NP);

    row_topk<<<BMT, 64, 0, stream>>>(logits, out_mix, out_clus, rowmax, rowsumInv);
    col_stats_part<<<dim3(4, 8, NB), 256, 0, stream>>>(logits, pmax, psum);
    col_stats_merge<<<dim3(4, NB), 256, 0, stream>>>(pmax, psum, colmax, colsumInv);

    // xs[b] = disp^T . xn[b]  -> split bf16  (A: logits transposed, col-softmax scale)
    gemm_mfma<2, 0, true, false><<<dim3(6, 8, NB), 256, 0, stream>>>(
        nullptr, nullptr, logits, xn, nullptr, xs_hi, xs_lo,
        NP, DD, MTOK, NP, DD, DD,
        (long)MTOK * NP, (long)MTOK * DD, (long)NP * DD,
        colmax, colsumInv, NP, nullptr, 0);

    // h[n] = gelu(xs_rows(n) . w1[n] + b1[n]) -> split bf16
    gemm_mfma<0, 2, true, true><<<dim3(16, 2, NEXP), 256, 0, stream>>>(
        xs_hi, xs_lo, nullptr, w1, nullptr, h_hi, h_lo,
        256, HH, DD, DD, HH, HH,
        0, (long)DD * HH, 0, nullptr, nullptr, 0, b1, HH);

    // ys[n] = h_rows(n) . w2[n] + b2[n]  -> f32 (consumed as B)
    gemm_mfma<0, 1, false, true><<<dim3(6, 2, NEXP), 256, 0, stream>>>(
        h_hi, h_lo, nullptr, w2, ys, nullptr, nullptr,
        256, DD, HH, HH, DD, DD,
        0, (long)HH * DD, 0, nullptr, nullptr, 0, b2, DD);

    // y[b] = comb . ys[b]  (A: logits rows, row-softmax scale) -> f32 out
    gemm_mfma<1, 0, false, false><<<dim3(6, 8, NB), 256, 0, stream>>>(
        nullptr, nullptr, logits, ys, out_y, nullptr, nullptr,
        MTOK, DD, NP, NP, DD, DD,
        (long)MTOK * NP, (long)NP * DD, (long)MTOK * DD,
        rowmax, rowsumInv, MTOK, nullptr, 0);
}

// Round 3
// 993.738 us; speedup vs baseline: 1.6097x; 1.0085x over previous
//
#include <hip/hip_runtime.h>
#include <cmath>

// ---------------- problem constants ----------------
// B=8, M=1024, D=768, N=32, P=32, K=8, H=2048
#define NB    8
#define MTOK  1024
#define BMT   8192      // B*M
#define DD    768
#define NEXP  32
#define PSLOT 32
#define NP    1024      // N*P
#define KTOP  8
#define HH    2048

#define LDS_S 40        // shorts per LDS row (80B, 16B-aligned); slots XOR-swizzled

typedef unsigned short ushort;
typedef __attribute__((ext_vector_type(8))) short short8v;   // 8 bf16 = 4 VGPR
typedef __attribute__((ext_vector_type(4))) short short4v;   // 8 bytes
typedef __attribute__((ext_vector_type(2))) short short2v;   // 4 bytes
typedef __attribute__((ext_vector_type(4))) float f32x4;

// f32 -> bf16 round-to-nearest-even
__device__ __forceinline__ ushort bf16_rne(float x) {
    unsigned u = __float_as_uint(x);
    unsigned r = (u + 0x7FFFu + ((u >> 16) & 1u)) >> 16;
    return (ushort)r;
}
__device__ __forceinline__ float bf16_to_f(ushort h) {
    return __uint_as_float(((unsigned)h) << 16);
}
__device__ __forceinline__ void split2(float x, ushort& hi, ushort& lo) {
    hi = bf16_rne(x);
    lo = bf16_rne(x - bf16_to_f(hi));
}

// ---------------- K1: token L2 normalize ----------------
__global__ __launch_bounds__(256) void norm_x(const float* __restrict__ x, float* __restrict__ xn) {
    int tok = blockIdx.x;
    int t = threadIdx.x;
    const float* p = x + (long)tok * DD;
    float v0 = p[t], v1 = p[t + 256], v2 = p[t + 512];
    float ss = v0 * v0 + v1 * v1 + v2 * v2;
#pragma unroll
    for (int o = 32; o; o >>= 1) ss += __shfl_xor(ss, o);
    __shared__ float sred[4];
    if ((t & 63) == 0) sred[t >> 6] = ss;
    __syncthreads();
    ss = sred[0] + sred[1] + sred[2] + sred[3];
    float inv = 1.0f / fmaxf(sqrtf(ss), 1e-12f);
    float* q = xn + (long)tok * DD;
    q[t] = v0 * inv; q[t + 256] = v1 * inv; q[t + 512] = v2 * inv;
}

// ---------------- K2: phi normalize (over D) + scale ----------------
__global__ __launch_bounds__(256) void norm_phi(const float* __restrict__ phi, const float* __restrict__ scale,
                                                float* __restrict__ phin) {
    int np = blockIdx.x * 256 + threadIdx.x;   // 0..1023
    float ss = 0.f;
    for (int d = 0; d < DD; ++d) {
        float v = phi[(long)d * NP + np];
        ss += v * v;
    }
    float sc = scale[0] / fmaxf(sqrtf(ss), 1e-12f);
    for (int d = 0; d < DD; ++d)
        phin[(long)d * NP + np] = phi[(long)d * NP + np] * sc;
}

// ---------------- K3: per-cluster sums (deterministic partials) ----------------
__global__ __launch_bounds__(256) void cluster_sum(const float* __restrict__ xn, const int* __restrict__ ca,
                                                   float* __restrict__ spart, float* __restrict__ cntpart) {
    __shared__ float s[NEXP][256];
    __shared__ float cnt[NEXP];
    int chunk = blockIdx.x, slice = blockIdx.y, t = threadIdx.x;
#pragma unroll
    for (int n = 0; n < NEXP; ++n) s[n][t] = 0.f;
    if (t < NEXP) cnt[t] = 0.f;
    __syncthreads();
    int tok0 = slice * 512;
    for (int i = 0; i < 512; ++i) {
        int tok = tok0 + i;
        int a = ca[tok * KTOP];
        float v = xn[(long)tok * DD + chunk * 256 + t];
        s[a][t] += v;
        if (chunk == 0 && t == 0) cnt[a] += 1.f;
    }
    __syncthreads();
    for (int n = 0; n < NEXP; ++n)
        spart[(long)slice * (NEXP * DD) + n * DD + chunk * 256 + t] = s[n][t];
    if (chunk == 0 && t < NEXP) cntpart[slice * NEXP + t] = cnt[t];
}

__global__ __launch_bounds__(256) void reduce_parts(const float* __restrict__ part, float* __restrict__ outv,
                                                    const float* __restrict__ cntpart, float* __restrict__ ccnt,
                                                    int doCnt) {
    int i = blockIdx.x * 256 + threadIdx.x;   // 0..24575
    float s = 0.f;
#pragma unroll
    for (int sl = 0; sl < 16; ++sl) s += part[(long)sl * (NEXP * DD) + i];
    outv[i] = s;
    if (doCnt && i < NEXP) {
        float c = 0.f;
#pragma unroll
        for (int sl = 0; sl < 16; ++sl) c += cntpart[sl * NEXP + i];
        ccnt[i] = c;
    }
}

// ---------------- K4: per-cluster MAD partials ----------------
__global__ __launch_bounds__(256) void cluster_mad(const float* __restrict__ xn, const int* __restrict__ ca,
                                                   const float* __restrict__ csum, const float* __restrict__ ccnt,
                                                   float* __restrict__ mpart) {
    __shared__ float md[NEXP][256];
    __shared__ float mean[NEXP][256];
    int chunk = blockIdx.x, slice = blockIdx.y, t = threadIdx.x;
#pragma unroll
    for (int n = 0; n < NEXP; ++n) {
        float c = ccnt[n];
        mean[n][t] = (c > 0.f) ? csum[n * DD + chunk * 256 + t] / c : 0.f;
        md[n][t] = 0.f;
    }
    __syncthreads();
    int tok0 = slice * 512;
    for (int i = 0; i < 512; ++i) {
        int tok = tok0 + i;
        int a = ca[tok * KTOP];
        float v = xn[(long)tok * DD + chunk * 256 + t];
        md[a][t] += fabsf(v - mean[a][t]);
    }
    __syncthreads();
    for (int n = 0; n < NEXP; ++n)
        mpart[(long)slice * (NEXP * DD) + n * DD + chunk * 256 + t] = md[n][t];
}

// ---------------- K5: W = normalize(clamp(1/(mad+0.35))) ----------------
__global__ __launch_bounds__(1024) void compute_W(const float* __restrict__ cmad, const float* __restrict__ ccnt,
                                                  float* __restrict__ W) {
    __shared__ float s[16];
    int t = threadIdx.x;
    auto block_sum = [&](float v) -> float {
#pragma unroll
        for (int o = 32; o; o >>= 1) v += __shfl_xor(v, o);
        if ((t & 63) == 0) s[t >> 6] = v;
        __syncthreads();
        float tot = 0.f;
#pragma unroll
        for (int i = 0; i < 16; ++i) tot += s[i];
        __syncthreads();
        return tot;
    };
    const int TOT = NEXP * DD;  // 24576
    float p = 0.f;
    for (int i = t; i < TOT; i += 1024) {
        int n = i / DD;
        float c = ccnt[n];
        float wm = (c > 0.f) ? cmad[i] / c : 0.f;
        p += 1.f / (wm + 0.35f);
    }
    float mean1 = block_sum(p) / (float)TOT;
    float clamp = 5.f * mean1;
    p = 0.f;
    for (int i = t; i < TOT; i += 1024) {
        int n = i / DD;
        float c = ccnt[n];
        float wm = (c > 0.f) ? cmad[i] / c : 0.f;
        p += fminf(1.f / (wm + 0.35f), clamp);
    }
    float mean2 = block_sum(p) / (float)TOT;
    float inv2 = 1.f / mean2;
    for (int i = t; i < TOT; i += 1024) {
        int n = i / DD;
        float c = ccnt[n];
        float wm = (c > 0.f) ? cmad[i] / c : 0.f;
        W[i] = fminf(1.f / (wm + 0.35f), clamp) * inv2;
    }
}

// ---------------- K6: xn *= W[assign] ----------------
__global__ __launch_bounds__(192) void apply_W(float* __restrict__ xn, const int* __restrict__ ca,
                                               const float* __restrict__ W) {
    int tok = blockIdx.x;
    int d4 = threadIdx.x * 4;
    int a = ca[tok * KTOP];
    float4 v = *reinterpret_cast<float4*>(xn + (long)tok * DD + d4);
    float4 w = *reinterpret_cast<const float4*>(W + a * DD + d4);
    v.x *= w.x; v.y *= w.y; v.z *= w.z; v.w *= w.w;
    *reinterpret_cast<float4*>(xn + (long)tok * DD + d4) = v;
}

// ---------------- MFMA split-bf16 GEMM: BM=256, BN=128, BK=32, 512 thr ----------------
// AMODE 0: A from pre-split bf16 pair, rows via expert remap.
// AMODE 1: A from f32, k-contiguous rows (+ optional per-row softmax scale).
// AMODE 2: A from f32 transposed ((r,k) at Af32[k*lda+r]) (+ optional per-row scale).
// EPI: 0 none, 1 +bias, 2 +bias+gelu.  WSPLIT: C -> bf16 pair.  CEMAP: expert remap C rows.
// Logical k-slot s (8 shorts) at physical slot s ^ ((row>>2)&3)  [bank-conflict swizzle].
template <int AMODE, bool SCALE, int EPI, bool WSPLIT, bool CEMAP>
__global__ __launch_bounds__(512, 4) void gemm_mfma(
    const ushort* __restrict__ Ahi, const ushort* __restrict__ Alo,
    const float* __restrict__ Af32, const float* __restrict__ B,
    float* __restrict__ Cf, ushort* __restrict__ Chi, ushort* __restrict__ Clo,
    int N, int K, int lda, int ldb, int ldc,
    long sA, long sB, long sC,
    const float* __restrict__ smax, const float* __restrict__ sinv, int sScale,
    const float* __restrict__ bias, int biasStride) {
    __shared__ __attribute__((aligned(16))) ushort Ah[256 * LDS_S];
    __shared__ __attribute__((aligned(16))) ushort Al[256 * LDS_S];
    __shared__ __attribute__((aligned(16))) ushort Bh[128 * LDS_S];
    __shared__ __attribute__((aligned(16))) ushort Bl[128 * LDS_S];

    // XCD-aware bijective remap (all grids are multiples of 8)
    int orig = blockIdx.x + gridDim.x * (blockIdx.y + gridDim.y * blockIdx.z);
    int nwg = gridDim.x * gridDim.y * gridDim.z;
    int wg = (orig & 7) * (nwg >> 3) + (orig >> 3);
    int bx = wg % gridDim.x;
    int rest = wg / gridDim.x;
    int by = rest % gridDim.y;
    int z  = rest / gridDim.y;
    const int m0 = by * 256;
    const int n0 = bx * 128;

    const int tid = threadIdx.x;
    const int lane = tid & 63, w = tid >> 6;
    const int wr = w >> 1, wc = w & 1;            // 4x2 waves of 64x64
    const int lr = lane & 15, kh = lane >> 4;
    const int xorv = (lr >> 2) & 3;               // frag-row swizzle key

    f32x4 acc[4][4];
#pragma unroll
    for (int i = 0; i < 4; ++i)
#pragma unroll
        for (int j = 0; j < 4; ++j) acc[i][j] = (f32x4)(0.f);

    const long zs = (long)z * sScale;

    for (int kk0 = 0; kk0 < K; kk0 += 32) {
        // ---------- stage A (256 rows x 32 k) ----------
        if constexpr (AMODE == 0) {
#pragma unroll
            for (int i = 0; i < 2; ++i) {
                int g = tid + i * 512;            // 0..1023
                int r = g >> 2, kg = g & 3;
                int rg = m0 + r;
                long roff = ((long)(rg >> 5) * NP + (long)z * PSLOT + (rg & 31)) * lda;
                long o = roff + kk0 + kg * 8;
                int ls = r * LDS_S + ((kg ^ ((r >> 2) & 3)) << 3);
                *reinterpret_cast<short8v*>(&Ah[ls]) = *reinterpret_cast<const short8v*>(Ahi + o);
                *reinterpret_cast<short8v*>(&Al[ls]) = *reinterpret_cast<const short8v*>(Alo + o);
            }
        } else if constexpr (AMODE == 1) {
#pragma unroll
            for (int i = 0; i < 4; ++i) {
                int g = tid + i * 512;            // 0..2047
                int r = g >> 3, kq = g & 7;
                int rg = m0 + r;
                float4 v = *reinterpret_cast<const float4*>(Af32 + (long)z * sA + (long)rg * lda + kk0 + kq * 4);
                float f0, f1, f2, f3;
                if constexpr (SCALE) {
                    float mx = smax[zs + rg], si = sinv[zs + rg];
                    f0 = __expf(v.x - mx) * si; f1 = __expf(v.y - mx) * si;
                    f2 = __expf(v.z - mx) * si; f3 = __expf(v.w - mx) * si;
                } else { f0 = v.x; f1 = v.y; f2 = v.z; f3 = v.w; }
                ushort h0,h1,h2,h3,l0,l1,l2,l3;
                split2(f0,h0,l0); split2(f1,h1,l1); split2(f2,h2,l2); split2(f3,h3,l3);
                int ls = r * LDS_S + (((kq >> 1) ^ ((r >> 2) & 3)) << 3) + ((kq & 1) << 2);
                *reinterpret_cast<short4v*>(&Ah[ls]) = short4v{(short)h0,(short)h1,(short)h2,(short)h3};
                *reinterpret_cast<short4v*>(&Al[ls]) = short4v{(short)l0,(short)l1,(short)l2,(short)l3};
            }
        } else {  // AMODE 2: transposed, 4x4 micro-transpose per thread
            int rq = (tid & 7) | ((tid >> 6) << 3);   // 0..63
            int kq = (tid >> 3) & 7;                  // 0..7
            float vals[4][4];                         // [dk][dr]
#pragma unroll
            for (int dk = 0; dk < 4; ++dk) {
                float4 v = *reinterpret_cast<const float4*>(
                    Af32 + (long)z * sA + (long)(kk0 + kq * 4 + dk) * lda + m0 + rq * 4);
                vals[dk][0] = v.x; vals[dk][1] = v.y; vals[dk][2] = v.z; vals[dk][3] = v.w;
            }
            float mxa[4], sia[4];
            if constexpr (SCALE) {
                float4 mx4 = *reinterpret_cast<const float4*>(smax + zs + m0 + rq * 4);
                float4 si4 = *reinterpret_cast<const float4*>(sinv + zs + m0 + rq * 4);
                mxa[0]=mx4.x; mxa[1]=mx4.y; mxa[2]=mx4.z; mxa[3]=mx4.w;
                sia[0]=si4.x; sia[1]=si4.y; sia[2]=si4.z; sia[3]=si4.w;
            }
            ushort h[4][4], l[4][4];
#pragma unroll
            for (int dk = 0; dk < 4; ++dk)
#pragma unroll
                for (int dr = 0; dr < 4; ++dr) {
                    float f = vals[dk][dr];
                    if constexpr (SCALE) f = __expf(f - mxa[dr]) * sia[dr];
                    split2(f, h[dk][dr], l[dk][dr]);
                }
#pragma unroll
            for (int dr = 0; dr < 4; ++dr) {
                int r = rq * 4 + dr;
                int ls = r * LDS_S + (((kq >> 1) ^ ((r >> 2) & 3)) << 3) + ((kq & 1) << 2);
                *reinterpret_cast<short4v*>(&Ah[ls]) =
                    short4v{(short)h[0][dr], (short)h[1][dr], (short)h[2][dr], (short)h[3][dr]};
                *reinterpret_cast<short4v*>(&Al[ls]) =
                    short4v{(short)l[0][dr], (short)l[1][dr], (short)l[2][dr], (short)l[3][dr]};
            }
        }
        // ---------- stage B (transposed f32 [k][n] -> LDS [n][k]) ----------
        {
            int kq  = (tid >> 3) & 7;
            int nq  = (tid & 7) | (((tid >> 6) & 3) << 3);   // 0..31
            int dkh = tid >> 8;                              // 0..1
            float va[2][4];                                  // [dd][dn]
#pragma unroll
            for (int dd = 0; dd < 2; ++dd) {
                float4 v = *reinterpret_cast<const float4*>(
                    B + (long)z * sB + (long)(kk0 + kq * 4 + dkh * 2 + dd) * ldb + n0 + nq * 4);
                va[dd][0] = v.x; va[dd][1] = v.y; va[dd][2] = v.z; va[dd][3] = v.w;
            }
            ushort h[2][4], l[2][4];
#pragma unroll
            for (int dd = 0; dd < 2; ++dd)
#pragma unroll
                for (int dn = 0; dn < 4; ++dn) split2(va[dd][dn], h[dd][dn], l[dd][dn]);
#pragma unroll
            for (int dn = 0; dn < 4; ++dn) {
                int r = nq * 4 + dn;
                int ls = r * LDS_S + (((kq >> 1) ^ ((r >> 2) & 3)) << 3) + ((kq & 1) << 2) + dkh * 2;
                *reinterpret_cast<short2v*>(&Bh[ls]) = short2v{(short)h[0][dn], (short)h[1][dn]};
                *reinterpret_cast<short2v*>(&Bl[ls]) = short2v{(short)l[0][dn], (short)l[1][dn]};
            }
        }
        __syncthreads();
        // ---------- fragments + MFMA ----------
        short8v b_h[4], b_l[4];
#pragma unroll
        for (int nj = 0; nj < 4; ++nj) {
            int row = wc * 64 + nj * 16 + lr;
            int ls = row * LDS_S + ((kh ^ xorv) << 3);
            b_h[nj] = *reinterpret_cast<const short8v*>(&Bh[ls]);
            b_l[nj] = *reinterpret_cast<const short8v*>(&Bl[ls]);
        }
#pragma unroll
        for (int mi = 0; mi < 4; ++mi) {
            int row = wr * 64 + mi * 16 + lr;
            int ls = row * LDS_S + ((kh ^ xorv) << 3);
            short8v ah = *reinterpret_cast<const short8v*>(&Ah[ls]);
            short8v al = *reinterpret_cast<const short8v*>(&Al[ls]);
#pragma unroll
            for (int nj = 0; nj < 4; ++nj) {
                acc[mi][nj] = __builtin_amdgcn_mfma_f32_16x16x32_bf16(ah, b_h[nj], acc[mi][nj], 0, 0, 0);
                acc[mi][nj] = __builtin_amdgcn_mfma_f32_16x16x32_bf16(ah, b_l[nj], acc[mi][nj], 0, 0, 0);
                acc[mi][nj] = __builtin_amdgcn_mfma_f32_16x16x32_bf16(al, b_h[nj], acc[mi][nj], 0, 0, 0);
            }
        }
        __syncthreads();
    }
    // ---------- epilogue ----------
#pragma unroll
    for (int mi = 0; mi < 4; ++mi)
#pragma unroll
        for (int j = 0; j < 4; ++j) {
            int rg = m0 + wr * 64 + mi * 16 + kh * 4 + j;
            long roff;
            if constexpr (CEMAP) roff = ((long)(rg >> 5) * NP + (long)z * PSLOT + (rg & 31)) * ldc;
            else                 roff = (long)z * sC + (long)rg * ldc;
#pragma unroll
            for (int nj = 0; nj < 4; ++nj) {
                int col = n0 + wc * 64 + nj * 16 + lr;
                float v = acc[mi][nj][j];
                if constexpr (EPI >= 1) v += bias[(long)z * biasStride + col];
                if constexpr (EPI == 2) v = 0.5f * v * (1.0f + erff(v * 0.70710678118654752f));
                if constexpr (WSPLIT) {
                    ushort h, l; split2(v, h, l);
                    Chi[roff + col] = h; Clo[roff + col] = l;
                } else {
                    Cf[roff + col] = v;
                }
            }
        }
}

// ---------------- K8: per-row top-8 + row softmax stats ----------------
__global__ __launch_bounds__(64) void row_topk(const float* __restrict__ logits,
                                               float* __restrict__ mix_out, float* __restrict__ clus_out,
                                               float* __restrict__ rowmax, float* __restrict__ rowsumInv) {
    int row = blockIdx.x;
    int lane = threadIdx.x;
    const float* p = logits + (long)row * NP;
    float v[16];
#pragma unroll
    for (int i = 0; i < 16; ++i) v[i] = p[lane + i * 64];
    float mx = v[0];
#pragma unroll
    for (int i = 1; i < 16; ++i) mx = fmaxf(mx, v[i]);
#pragma unroll
    for (int o = 32; o; o >>= 1) mx = fmaxf(mx, __shfl_xor(mx, o));
    float s = 0.f;
#pragma unroll
    for (int i = 0; i < 16; ++i) s += __expf(v[i] - mx);
#pragma unroll
    for (int o = 32; o; o >>= 1) s += __shfl_xor(s, o);
    if (lane == 0) { rowmax[row] = mx; rowsumInv[row] = 1.0f / s; }
#pragma unroll
    for (int k = 0; k < KTOP; ++k) {
        float bv = -INFINITY; int bi = 1 << 30;
#pragma unroll
        for (int i = 0; i < 16; ++i) {
            if (v[i] > bv) { bv = v[i]; bi = lane + i * 64; }
        }
#pragma unroll
        for (int o = 32; o; o >>= 1) {
            float ov = __shfl_xor(bv, o); int oi = __shfl_xor(bi, o);
            if (ov > bv || (ov == bv && oi < bi)) { bv = ov; bi = oi; }
        }
        int owner = bi & 63, slot = bi >> 6;
        if (lane == owner) {
#pragma unroll
            for (int i = 0; i < 16; ++i) if (slot == i) v[i] = -INFINITY;
        }
        if (lane == k) {
            mix_out[(long)row * KTOP + k] = bv;
            clus_out[(long)row * KTOP + k] = (float)(bi >> 5);
        }
    }
}

// ---------------- K9: column softmax stats ----------------
__global__ __launch_bounds__(256) void col_stats_part(const float* __restrict__ logits,
                                                      float* __restrict__ pmax, float* __restrict__ psum) {
    int b = blockIdx.z, ms = blockIdx.y, npc = blockIdx.x;
    int np = npc * 256 + threadIdx.x;
    const float* p = logits + ((long)b * MTOK + ms * 128) * NP + np;
    float mx = -INFINITY, s = 0.f;
    for (int m = 0; m < 128; ++m) {
        float v = p[(long)m * NP];
        float nm = fmaxf(mx, v);
        s = s * __expf(mx - nm) + __expf(v - nm);
        mx = nm;
    }
    long o = ((long)b * 8 + ms) * NP + np;
    pmax[o] = mx; psum[o] = s;
}

__global__ __launch_bounds__(256) void col_stats_merge(const float* __restrict__ pmax, const float* __restrict__ psum,
                                                       float* __restrict__ cmax, float* __restrict__ csumInv) {
    int b = blockIdx.y;
    int np = blockIdx.x * 256 + threadIdx.x;
    float mx = -INFINITY;
#pragma unroll
    for (int ms = 0; ms < 8; ++ms) mx = fmaxf(mx, pmax[((long)b * 8 + ms) * NP + np]);
    float s = 0.f;
#pragma unroll
    for (int ms = 0; ms < 8; ++ms) {
        long o = ((long)b * 8 + ms) * NP + np;
        s += psum[o] * __expf(pmax[o] - mx);
    }
    cmax[(long)b * NP + np] = mx;
    csumInv[(long)b * NP + np] = 1.0f / s;
}

// ---------------- launch ----------------
extern "C" void kernel_launch(void* const* d_in, const int* in_sizes, int n_in,
                              void* d_out, int out_size, void* d_ws, size_t ws_size,
                              hipStream_t stream) {
    const float* x    = (const float*)d_in[0];
    const int*   ca   = (const int*)d_in[1];
    const float* phi  = (const float*)d_in[2];
    const float* scale= (const float*)d_in[3];
    const float* w1   = (const float*)d_in[4];
    const float* b1   = (const float*)d_in[5];
    const float* w2   = (const float*)d_in[6];
    const float* b2   = (const float*)d_in[7];
    float* out = (float*)d_out;
    float* ws  = (float*)d_ws;

    float* xn        = ws;                    // 6291456 f32
    float* phin      = xn + 6291456;          // 786432
    float* logits    = phin + 786432;         // 8388608
    ushort* xs_hi    = (ushort*)(logits + 8388608);   // 6291456 shorts
    ushort* xs_lo    = xs_hi + 6291456;               // 6291456 shorts
    ushort* h_hi     = (ushort*)((float*)xs_hi + 6291456);  // 16777216 shorts
    ushort* h_lo     = h_hi + 16777216;
    float* after_h   = (float*)xs_hi + 6291456 + 16777216;
    float* rowmax    = after_h;               // 8192
    float* rowsumInv = rowmax + 8192;
    float* colmax    = rowsumInv + 8192;
    float* colsumInv = colmax + 8192;
    float* pmax      = colsumInv + 8192;      // 65536
    float* psum      = pmax + 65536;          // 65536
    float* csum      = psum + 65536;          // 24576
    float* cmad      = csum + 24576;          // 24576
    float* Wbuf      = cmad + 24576;          // 24576
    float* ccnt      = Wbuf + 24576;          // 64
    float* spart     = ccnt + 64;             // 393216
    float* mpart     = spart + 393216;        // 393216
    float* cntpart   = mpart + 393216;        // 512
    float* ys        = xn;                    // alias: xn dead after xs GEMM

    float* out_y    = out;
    float* out_mix  = out + 6291456;
    float* out_clus = out + 6291456 + 65536;

    norm_x<<<BMT, 256, 0, stream>>>(x, xn);
    norm_phi<<<4, 256, 0, stream>>>(phi, scale, phin);

    cluster_sum<<<dim3(3, 16), 256, 0, stream>>>(xn, ca, spart, cntpart);
    reduce_parts<<<96, 256, 0, stream>>>(spart, csum, cntpart, ccnt, 1);
    cluster_mad<<<dim3(3, 16), 256, 0, stream>>>(xn, ca, csum, ccnt, mpart);
    reduce_parts<<<96, 256, 0, stream>>>(mpart, cmad, nullptr, nullptr, 0);
    compute_W<<<1, 1024, 0, stream>>>(cmad, ccnt, Wbuf);
    apply_W<<<BMT, 192, 0, stream>>>(xn, ca, Wbuf);

    // logits = xn_w [8192x768] . phin [768x1024]  (split-bf16 MFMA, f32-accurate)
    gemm_mfma<1, false, 0, false, false><<<dim3(8, 32, 1), 512, 0, stream>>>(
        nullptr, nullptr, xn, phin, logits, nullptr, nullptr,
        NP, DD, DD, NP, NP, 0, 0, 0, nullptr, nullptr, 0, nullptr, 0);

    row_topk<<<BMT, 64, 0, stream>>>(logits, out_mix, out_clus, rowmax, rowsumInv);
    col_stats_part<<<dim3(4, 8, NB), 256, 0, stream>>>(logits, pmax, psum);
    col_stats_merge<<<dim3(4, NB), 256, 0, stream>>>(pmax, psum, colmax, colsumInv);

    // xs[b] = disp^T . xn[b] -> split bf16 pair
    gemm_mfma<2, true, 0, true, false><<<dim3(6, 4, NB), 512, 0, stream>>>(
        nullptr, nullptr, logits, xn, nullptr, xs_hi, xs_lo,
        DD, MTOK, NP, DD, DD,
        (long)MTOK * NP, (long)MTOK * DD, (long)NP * DD,
        colmax, colsumInv, NP, nullptr, 0);

    // h[n] = gelu(xs_rows(n) . w1[n] + b1[n]) -> split bf16 pair
    gemm_mfma<0, false, 2, true, true><<<dim3(16, 1, NEXP), 512, 0, stream>>>(
        xs_hi, xs_lo, nullptr, w1, nullptr, h_hi, h_lo,
        HH, DD, DD, HH, HH,
        0, (long)DD * HH, 0, nullptr, nullptr, 0, b1, HH);

    // ys[n] = h_rows(n) . w2[n] + b2[n] -> f32
    gemm_mfma<0, false, 1, false, true><<<dim3(6, 1, NEXP), 512, 0, stream>>>(
        h_hi, h_lo, nullptr, w2, ys, nullptr, nullptr,
        DD, HH, HH, DD, DD,
        0, (long)HH * DD, 0, nullptr, nullptr, 0, b2, DD);

    // y[b] = comb . ys[b] -> f32 out
    gemm_mfma<1, true, 0, false, false><<<dim3(6, 4, NB), 512, 0, stream>>>(
        nullptr, nullptr, logits, ys, out_y, nullptr, nullptr,
        DD, NP, NP, DD, DD,
        (long)MTOK * NP, (long)NP * DD, (long)MTOK * DD,
        rowmax, rowsumInv, MTOK, nullptr, 0);
}